// Round 9
// baseline (61797.620 us; speedup 1.0000x reference)
//
#include <hip/hip_runtime.h>
#include <hip/hip_fp16.h>

typedef _Float16 f16;
typedef _Float16 f16x8 __attribute__((ext_vector_type(8)));
typedef _Float16 f16x4 __attribute__((ext_vector_type(4)));
typedef float f32x4 __attribute__((ext_vector_type(4)));
typedef int int4v __attribute__((ext_vector_type(4)));

#define DI static __device__ __forceinline__

constexpr int N2 = 257 * 257;
#define LSTRIDE ((size_t)254 * 32 * 768)
#define HWREG_XCC_ID 63508  // hwreg(id=20, offset=0, size=32)
#define FSTRIDE 256         // flag steps per layer (4KB-aligned layer regions)

DI f32x4 mfma16(f16x8 a, f16x8 b, f32x4 c) {
  return __builtin_amdgcn_mfma_f32_16x16x32_f16(a, b, c, 0, 0, 0);
}
DI f16x8 ldg8(const f16* p) { return *reinterpret_cast<const f16x8*>(p); }
DI f16x8 cvt8(const float* s) {
  f16x8 v;
#pragma unroll
  for (int j = 0; j < 8; ++j) v[j] = (f16)s[j];
  return v;
}
DI double invfact(int k) {
  double f = 1.0;
  for (int i = 2; i <= k; ++i) f *= (double)i;
  return 1.0 / f;
}

// ---- visibility helpers ----
DI void st_d_sc1(double* p, double v) {
  asm volatile("global_store_dwordx2 %0, %1, off sc1" :: "v"(p), "v"(v) : "memory");
}
DI void st_f_sc1(float* p, float v) {
  asm volatile("global_store_dword %0, %1, off sc1" :: "v"(p), "v"(v) : "memory");
}
DI void st_h_sc1(f16* p, f16 v) {
  asm volatile("global_store_short %0, %1, off sc1" :: "v"(p), "v"(v) : "memory");
}
DI void st_b_plain(unsigned char* p, int v) {  // flag byte -> local L2 (fire & forget)
  asm volatile("global_store_byte %0, %1, off" :: "v"(p), "v"(v) : "memory");
}
DI void st_b_sc1(unsigned char* p, int v) {  // flag byte -> LLC (fire & forget)
  asm volatile("global_store_byte %0, %1, off sc1" :: "v"(p), "v"(v) : "memory");
}
DI void st8_sc1(f16* p, f16x4 v) {  // 8B -> LLC + full drain (slow path)
  asm volatile("global_store_dwordx2 %0, %1, off sc1\n\ts_waitcnt vmcnt(0)"
               :: "v"(p), "v"(v) : "memory");
}
DI void st8_plain(f16* p, f16x4 v) {  // 8B -> local L2 + drain
  asm volatile("global_store_dwordx2 %0, %1, off\n\ts_waitcnt vmcnt(0)"
               :: "v"(p), "v"(v) : "memory");
}
DI void st8_fast(f16* p, f16x4 v) {
  // plain (local L2) + sc1 (write-through LLC); vmcnt(1): in-order retirement =>
  // the PLAIN (older) store has completed; the sc1 store drains later.
  asm volatile(
      "global_store_dwordx2 %0, %1, off\n\t"
      "global_store_dwordx2 %0, %1, off sc1\n\t"
      "s_waitcnt vmcnt(1)"
      :: "v"(p), "v"(v) : "memory");
}
DI int ld_llc(const int* p) {
  return __hip_atomic_load(p, __ATOMIC_RELAXED, __HIP_MEMORY_SCOPE_AGENT);
}
DI void add_llc(int* p) {
  __hip_atomic_fetch_add(p, 1, __ATOMIC_RELAXED, __HIP_MEMORY_SCOPE_AGENT);
}
DI void drain_vm() { asm volatile("s_waitcnt vmcnt(0)" ::: "memory"); }
DI void membar() {
  __builtin_amdgcn_sched_barrier(0);
  asm volatile("" ::: "memory");
}
DI bool l16ok(int4v a) {
  return a.x == 0x01010101 && a.y == 0x01010101 && a.z == 0x01010101 && a.w == 0x01010101;
}
// two-phase own-layer poll: (A) local L2 line only — the fast path;
// (B) local OR LLC line — safety net (wrong co-location verdict degrades, not corrupts).
DI void poll_own2(const int* ff, const int* fl) {
  for (int it = 0; it < 2048; ++it) {  // phase A: pure local-L2 RTT
    int4v a;
    asm volatile("global_load_dwordx4 %0, %1, off sc0\n\ts_waitcnt vmcnt(0)"
                 : "=v"(a) : "v"(ff) : "memory");
    if (l16ok(a)) return;
    __builtin_amdgcn_s_sleep(1);
  }
  for (int it = 0; it < (1 << 14); ++it) {  // phase B: accept either line
    int4v a, b;
    asm volatile(
        "global_load_dwordx4 %0, %2, off sc0\n\t"
        "global_load_dwordx4 %1, %3, off sc1\n\t"
        "s_waitcnt vmcnt(0)"
        : "=&v"(a), "=&v"(b) : "v"(ff), "v"(fl) : "memory");
    if (l16ok(a) || l16ok(b)) return;
    __builtin_amdgcn_s_sleep(1);
  }
}
// slow-view consumer: LLC lines only (r5-proven path)
template <bool HASP>
DI void poll_slow(const int* fl, const int* pl) {
  for (int it = 0; it < (1 << 14); ++it) {
    int4v b, c;
    asm volatile(
        "global_load_dwordx4 %0, %2, off sc1\n\t"
        "global_load_dwordx4 %1, %3, off sc1\n\t"
        "s_waitcnt vmcnt(0)"
        : "=&v"(b), "=&v"(c)
        : "v"(fl), "v"(pl) : "memory");
    bool prv = HASP ? l16ok(c) : true;
    if (l16ok(b) & prv) return;
    __builtin_amdgcn_s_sleep(1);
  }
}
DI float tanh_fast(float x) {
  x = fminf(9.f, fmaxf(-9.f, x));
  float e = __expf(2.f * x);
  return __fdividef(e - 1.f, e + 1.f);
}

// fence-free counting barrier (k_setup only)
DI void gridbar_nf(int* bar, int nwg) {
  drain_vm();
  __syncthreads();
  if (threadIdx.x == 0) {
    int g = ld_llc(bar + 1);
    int old = __hip_atomic_fetch_add(bar, 1, __ATOMIC_RELAXED, __HIP_MEMORY_SCOPE_AGENT);
    if (old == nwg - 1) {
      __hip_atomic_store(bar, 0, __ATOMIC_RELAXED, __HIP_MEMORY_SCOPE_AGENT);
      add_llc(bar + 1);
    } else {
      for (int it = 0; it < (1 << 14) && ld_llc(bar + 1) == g; ++it)
        __builtin_amdgcn_s_sleep(1);
    }
  }
  __syncthreads();
}

// D = A*B (257x257 fp64), optional fused Taylor block; output via sc1 stores.
DI void mm257(double* __restrict__ D, const double* __restrict__ A, const double* __restrict__ Bm,
              int fj, const double* __restrict__ T1, const double* __restrict__ T2,
              const double* __restrict__ T3, int gtid, int nth) {
  double c0 = 0, c1 = 0, c2 = 0, c3 = 0;
  if (fj >= 0) {
    c0 = invfact(4 * fj); c1 = invfact(4 * fj + 1);
    c2 = invfact(4 * fj + 2); c3 = invfact(4 * fj + 3);
  }
  for (int e = gtid; e < N2; e += nth) {
    int i = e / 257, j = e - i * 257;
    const double* ar = A + (size_t)i * 257;
    const double* bc = Bm + j;
    double s0 = 0, s1 = 0, s2 = 0, s3 = 0;
    for (int k = 0; k < 256; k += 4) {
      s0 = fma(ar[k], bc[(size_t)k * 257], s0);
      s1 = fma(ar[k + 1], bc[(size_t)(k + 1) * 257], s1);
      s2 = fma(ar[k + 2], bc[(size_t)(k + 2) * 257], s2);
      s3 = fma(ar[k + 3], bc[(size_t)(k + 3) * 257], s3);
    }
    double s = ((s0 + s1) + (s2 + s3)) + ar[256] * bc[(size_t)256 * 257];
    if (fj >= 0) s += c0 * ((i == j) ? 1.0 : 0.0) + c1 * T1[e] + c2 * T2[e] + c3 * T3[e];
    st_d_sc1(D + e, s);
  }
}

// ---------------- K1: expm + all precomputation (128 WGs, fence-free) ----------------
__global__ __launch_bounds__(256) void k_setup(
    const float* __restrict__ dayW, const float* __restrict__ ex0, const float* __restrict__ Wx0,
    const float* __restrict__ exr, const float* __restrict__ Wxr,
    const float* __restrict__ eh, const float* __restrict__ em,
    const float* __restrict__ Wh, const float* __restrict__ Wm, const float* __restrict__ outW,
    double* __restrict__ X, float* __restrict__ w1f, float* __restrict__ AWt,
    float* __restrict__ btf, f16* __restrict__ gbuf, f16* __restrict__ wxcat,
    f16* __restrict__ outw, f16* __restrict__ dayWt, int* __restrict__ bar) {
  const int gtid = blockIdx.x * 256 + threadIdx.x;
  const int nth = 128 * 256;
  double* Ms = X;
  double* M2 = X + N2;
  double* M3 = X + 2 * N2;
  double* M4 = X + 3 * N2;
  double* H = X + 4 * N2;   // H0..H6
  double* S = X + 11 * N2;  // S0..S5

  for (int e = gtid; e < N2; e += nth) {
    int i = e / 257, j = e - i * 257;
    double v = 0.0;
    if (i < 256) {
      double R = (2.0 * i + 1.0) / 256.0;
      if (j < 256) v = R * ((i < j) ? -1.0 : (((i - j) & 1) ? 1.0 : -1.0));
      else v = R * ((i & 1) ? -1.0 : 1.0);
    }
    st_d_sc1(Ms + e, v / 64.0);  // s = 6
  }
  for (int e = gtid; e < 576 * 896; e += nth) {  // wxcat [576][7168] = [Wx0 | ex0 | 0]
    int n = e / 896, kc = (e - n * 896) * 8;
    f16x8 v;
    if (n < 512) v = cvt8(Wx0 + (size_t)n * 7168 + kc);
    else if (n == 512) v = cvt8(ex0 + kc);
    else {
#pragma unroll
      for (int j = 0; j < 8; ++j) v[j] = (f16)0.f;
    }
    *reinterpret_cast<f16x8*>(wxcat + (size_t)n * 7168 + kc) = v;
  }
  for (int e = gtid; e < 48 * 64; e += nth) {  // outw [48][512]
    int n = e / 64, kc = (e - n * 64) * 8;
    f16x8 v;
    if (n < 41) v = cvt8(outW + (size_t)n * 512 + kc);
    else {
#pragma unroll
      for (int j = 0; j < 8; ++j) v[j] = (f16)0.f;
    }
    *reinterpret_cast<f16x8*>(outw + (size_t)n * 512 + kc) = v;
  }
  {  // dayWt[D][n][k] = dayW[D][k][n] via LDS tile transpose
    __shared__ float tile[64][65];
    for (int tt = blockIdx.x; tt < 24 * 64; tt += 128) {
      int D = tt >> 6; int r = tt & 63; int kb = (r >> 3) * 64; int nb = (r & 7) * 64;
      __syncthreads();
      for (int q = 0; q < 16; ++q) {
        int idx = threadIdx.x + q * 256; int kk = idx >> 6; int nn = idx & 63;
        tile[kk][nn] = dayW[(size_t)D * 262144 + (size_t)(kb + kk) * 512 + nb + nn];
      }
      __syncthreads();
      for (int q = 0; q < 2; ++q) {
        int cidx = threadIdx.x + q * 256; int nn = cidx >> 3; int kc = (cidx & 7) * 8;
        f16x8 v;
#pragma unroll
        for (int jj = 0; jj < 8; ++jj) v[jj] = (f16)tile[kc + jj][nn];
        *reinterpret_cast<f16x8*>(dayWt + (size_t)D * 262144 + (size_t)(nb + nn) * 512 + kb + kc) = v;
      }
    }
    __syncthreads();
  }
  gridbar_nf(bar, 128);

  mm257(M2, Ms, Ms, -1, Ms, Ms, Ms, gtid, nth); gridbar_nf(bar, 128);
  mm257(M3, M2, Ms, -1, Ms, Ms, Ms, gtid, nth); gridbar_nf(bar, 128);
  mm257(M4, M2, M2, -1, Ms, Ms, Ms, gtid, nth);
  for (int e = gtid; e < N2; e += nth) {  // H0 = c24*I
    int i = e / 257, j = e - i * 257;
    st_d_sc1(H + e, (i == j) ? invfact(24) : 0.0);
  }
  gridbar_nf(bar, 128);
  for (int k = 0; k < 6; ++k) {
    mm257(H + (size_t)(k + 1) * N2, H + (size_t)k * N2, M4, 5 - k, Ms, M2, M3, gtid, nth);
    gridbar_nf(bar, 128);
  }
  {
    const double* Ssrc = H + (size_t)6 * N2;
    for (int k = 0; k < 6; ++k) {
      mm257(S + (size_t)k * N2, Ssrc, Ssrc, -1, Ms, Ms, Ms, gtid, nth);
      gridbar_nf(bar, 128);
      Ssrc = S + (size_t)k * N2;
    }
  }
  const double* E = S + (size_t)5 * N2;  // exp(aug)

  for (int e = gtid; e < 256; e += nth) st_f_sc1(btf + e, (float)E[(size_t)e * 257 + 256]);
  for (int e = gtid; e < 5 * 512; e += nth) {
    int l = e / 512, n = e - l * 512;
    const float* wm = Wm + ((size_t)l * 512 + n) * 256;
    float s = 0.f;
    for (int j = 0; j < 256; ++j) s += (float)E[(size_t)j * 257 + 256] * wm[j];
    st_f_sc1(w1f + e, s);
  }
  for (int e = gtid; e < 5 * 512 * 256; e += nth) {
    int l = e / (512 * 256); int r = e - l * 512 * 256; int n = r >> 8; int i = r & 255;
    const double* Ec = E + i;
    const float* wm = Wm + ((size_t)l * 512 + n) * 256;
    float s0 = 0, s1 = 0, s2 = 0, s3 = 0;
    for (int j = 0; j < 256; j += 4) {
      s0 += (float)Ec[(size_t)j * 257] * wm[j];
      s1 += (float)Ec[(size_t)(j + 1) * 257] * wm[j + 1];
      s2 += (float)Ec[(size_t)(j + 2) * 257] * wm[j + 2];
      s3 += (float)Ec[(size_t)(j + 3) * 257] * wm[j + 3];
    }
    st_f_sc1(AWt + e, (s0 + s1) + (s2 + s3));
  }
  gridbar_nf(bar, 128);

  for (int e = gtid; e < 5 * 768 * 160; e += nth) {  // gbuf fill
    int l = e / (768 * 160); int r = e - l * 768 * 160; int n = r / 160; int k = (r - n * 160) * 8;
    if (l == 0 && k >= 768) continue;
    f16x8 v;
    if (n < 512) {
      float w1n = w1f[l * 512 + n];
      if (k < 512) {
        const float* a = Wh + ((size_t)l * 512 + n) * 512 + k;
        const float* b = eh + (size_t)l * 512 + k;
#pragma unroll
        for (int jj = 0; jj < 8; ++jj) v[jj] = (f16)(a[jj] + b[jj] * w1n);
      } else if (k < 768) {
        int i = k - 512;
        const float* a = AWt + ((size_t)l * 512 + n) * 256 + i;
        const float* b = em + (size_t)l * 256 + i;
#pragma unroll
        for (int jj = 0; jj < 8; ++jj) v[jj] = (f16)(a[jj] + b[jj] * w1n);
      } else {
        int d = k - 768;
        const float* a = Wxr + ((size_t)(l - 1) * 512 + n) * 512 + d;
        const float* b = exr + (size_t)(l - 1) * 512 + d;
#pragma unroll
        for (int jj = 0; jj < 8; ++jj) v[jj] = (f16)(a[jj] + b[jj] * w1n);
      }
    } else {
      int jm = n - 512;
      float btn = btf[jm];
      if (k < 512) {
        const float* b = eh + (size_t)l * 512 + k;
#pragma unroll
        for (int jj = 0; jj < 8; ++jj) v[jj] = (f16)(b[jj] * btn);
      } else if (k < 768) {
        int i = k - 512;
        const double* a = E + (size_t)jm * 257 + i;
        const float* b = em + (size_t)l * 256 + i;
#pragma unroll
        for (int jj = 0; jj < 8; ++jj) v[jj] = (f16)((float)a[jj] + b[jj] * btn);
      } else {
        int d = k - 768;
        const float* b = exr + (size_t)(l - 1) * 512 + d;
#pragma unroll
        for (int jj = 0; jj < 8; ++jj) v[jj] = (f16)(b[jj] * btn);
      }
    }
    *reinterpret_cast<f16x8*>(gbuf + ((size_t)l * 768 + n) * 1280 + k) = v;
  }
}

// ---------------- K2: day-specific linear + softsign -> h1 (f16) ----------------
__global__ __launch_bounds__(256) void k_day(const float* __restrict__ x,
    const int* __restrict__ dayIdx, const float* __restrict__ dayb,
    const f16* __restrict__ dayWt, f16* __restrict__ h1) {
  __shared__ f16 As[64][40];
  __shared__ f16 Bs[256][40];
  const int bid = blockIdx.x;
  const int b = bid >> 5; const int r = bid & 31;
  const int t0 = (r >> 1) * 64; const int n0 = (r & 1) * 256;
  const int D = dayIdx[b];
  const int tid = threadIdx.x, lane = tid & 63, w = tid >> 6, q4 = lane >> 4;
  const float* xb = x + ((size_t)b * 1024 + t0) * 512;
  const f16* Wt = dayWt + (size_t)D * 262144 + (size_t)n0 * 512;
  f32x4 acc[16];
#pragma unroll
  for (int i = 0; i < 16; ++i) acc[i] = (f32x4){0.f, 0.f, 0.f, 0.f};
  for (int kt = 0; kt < 16; ++kt) {
    const int k0 = kt * 32;
    __syncthreads();
    { int row = tid >> 2, c8 = (tid & 3) * 8;
      *reinterpret_cast<f16x8*>(&As[row][c8]) = cvt8(xb + (size_t)row * 512 + k0 + c8); }
    for (int q = 0; q < 4; ++q) {
      int idx = tid + q * 256; int row = idx >> 2; int c8 = (idx & 3) * 8;
      *reinterpret_cast<f16x8*>(&Bs[row][c8]) = ldg8(Wt + (size_t)row * 512 + k0 + c8);
    }
    __syncthreads();
    f16x8 a = *reinterpret_cast<const f16x8*>(&As[w * 16 + (lane & 15)][q4 * 8]);
#pragma unroll
    for (int nt2 = 0; nt2 < 16; ++nt2) {
      f16x8 bb = *reinterpret_cast<const f16x8*>(&Bs[nt2 * 16 + (lane & 15)][q4 * 8]);
      acc[nt2] = mfma16(a, bb, acc[nt2]);
    }
  }
#pragma unroll
  for (int nt2 = 0; nt2 < 16; ++nt2) {
    int n = n0 + nt2 * 16 + (lane & 15);
    float db = dayb[(size_t)D * 512 + n];
#pragma unroll
    for (int i = 0; i < 4; ++i) {
      int t = t0 + w * 16 + q4 * 4 + i;
      float v = acc[nt2][i] + db;
      v = v / (1.f + fabsf(v));
      h1[((size_t)b * 1024 + t) * 512 + n] = (f16)v;
    }
  }
}

// ---------------- K3: layer-0 input GEMM -> xw0 [8192][576] f32 ----------------
__global__ __launch_bounds__(256) void k_xw0(const f16* __restrict__ h1,
    const f16* __restrict__ wxcat, float* __restrict__ xw0) {
  __shared__ f16 As[128][40];
  __shared__ f16 Bs[96][40];
  const int bid = blockIdx.x;
  const int mt = bid / 6; const int nb = bid - mt * 6;
  const int m0 = mt * 128; const int n0 = nb * 96;
  const int tid = threadIdx.x, lane = tid & 63, w = tid >> 6, q4 = lane >> 4;
  f32x4 acc[2][6];
#pragma unroll
  for (int a = 0; a < 2; ++a)
#pragma unroll
    for (int b = 0; b < 6; ++b) acc[a][b] = (f32x4){0.f, 0.f, 0.f, 0.f};
  for (int kt = 0; kt < 224; ++kt) {
    const int k0 = kt * 32; const int p = k0 >> 9; const int kd = k0 & 511;
    __syncthreads();
    for (int q = 0; q < 2; ++q) {
      int idx = tid + q * 256; int row = idx >> 2; int c8 = (idx & 3) * 8;
      int m = m0 + row; int b = m >> 8; int tp = m & 255; if (tp > 252) tp = 252;
      *reinterpret_cast<f16x8*>(&As[row][c8]) =
          ldg8(h1 + ((size_t)b * 1024 + (size_t)tp * 4 + p) * 512 + kd + c8);
    }
    for (int q = 0; q < 2; ++q) {
      int idx = tid + q * 256;
      if (idx < 384) {
        int row = idx >> 2; int c8 = (idx & 3) * 8;
        *reinterpret_cast<f16x8*>(&Bs[row][c8]) =
            ldg8(wxcat + (size_t)(n0 + row) * 7168 + k0 + c8);
      }
    }
    __syncthreads();
#pragma unroll
    for (int mb = 0; mb < 2; ++mb) {
      f16x8 a = *reinterpret_cast<const f16x8*>(&As[w * 32 + mb * 16 + (lane & 15)][q4 * 8]);
#pragma unroll
      for (int nt2 = 0; nt2 < 6; ++nt2) {
        f16x8 bb = *reinterpret_cast<const f16x8*>(&Bs[nt2 * 16 + (lane & 15)][q4 * 8]);
        acc[mb][nt2] = mfma16(a, bb, acc[mb][nt2]);
      }
    }
  }
#pragma unroll
  for (int mb = 0; mb < 2; ++mb)
#pragma unroll
    for (int nt2 = 0; nt2 < 6; ++nt2)
#pragma unroll
      for (int i = 0; i < 4; ++i) {
        int m = m0 + w * 32 + mb * 16 + q4 * 4 + i;
        int n = n0 + nt2 * 16 + (lane & 15);
        xw0[(size_t)m * 576 + n] = acc[mb][nt2][i];
      }
}

// ---------------- K4: pipelined LMU recurrence (XCD-local critical path) ----------------
template <int KK, bool FAST>
DI void rec_run(int l, int c, int tid, const f16* __restrict__ gbuf, f16* __restrict__ sbuf,
                const float* __restrict__ xw0, const float* __restrict__ w1f,
                const float* __restrict__ btf, const float* __restrict__ h0,
                const float* __restrict__ m0, unsigned char* ffl, unsigned char* fll,
                f16* bflds, f16* smtile) {
  const int lane = tid & 63, w = tid >> 6;
  const int mb = w / 3, nt = w % 3;
  const int nbase = c * 48 + nt * 16;
  const int ncol = nbase + (lane & 15);
  const int q4 = lane >> 4;

  // ---- t=0 state init ----
  for (int r = tid; r < 32 * 48; r += 384) {
    int row = r / 48; int col = c * 48 + (r - row * 48);
    float v = (col < 512) ? h0[(size_t)l * 512 + col] : m0[(size_t)l * 256 + col - 512];
    f16* p = sbuf + (size_t)l * LSTRIDE + (size_t)row * 768 + col;
    if (FAST) *p = (f16)v;          // only own layer reads t=0 -> own-XCD L2 suffices
    else st_h_sc1(p, (f16)v);
  }

  // ---- weights into registers (+ LDS for the x-tail of KK=40) ----
  const f16* gb = gbuf + ((size_t)l * 768 + ncol) * 1280 + (size_t)q4 * 8;
  constexpr int NREG = (KK > 32) ? 32 : KK;
  f16x8 bf[NREG];
#pragma unroll
  for (int kk = 0; kk < NREG; ++kk) bf[kk] = ldg8(gb + (size_t)kk * 32);
  if (KK == 40) {
#pragma unroll
    for (int kk = 32; kk < 40; ++kk) {
      f16x8 v = ldg8(gb + (size_t)kk * 32);
      *reinterpret_cast<f16x8*>(bflds + ((size_t)(w * 8 + (kk - 32)) * 64 + lane) * 8) = v;
    }
  }
  float w1n = 0.f, btn = 0.f;
  if (KK == 24) {
    if (ncol < 512) w1n = w1f[ncol];
    else btn = btf[ncol - 512];
  }
  drain_vm();       // every thread drains its own init stores
  __syncthreads();  // + bflds visible
  if (tid == 0) {   // both flag lines, both modes (mixed-mode interop)
    st_b_plain(ffl + (size_t)(l * FSTRIDE) * 16 + c, 1);
    st_b_sc1(fll + (size_t)(l * FSTRIDE) * 16 + c, 1);
  }

  int pready = 0;  // prev-layer flags confirmed for all step indices <= pready (tid0 only)

  for (int t = 0; t < 253; ++t) {
    // flag-independent xw0 bias loads (layer 0 only; plain, L2-cached)
    float xadd[4];
    if (KK == 24) {
#pragma unroll
      for (int i = 0; i < 4; ++i) {
        const int brow = mb * 16 + q4 * 4 + i;
        const float* xr = xw0 + ((size_t)brow * 256 + t) * 576;
        float xe = xr[512];
        xadd[i] = (ncol < 512) ? (xr[ncol] + xe * w1n) : (xe * btn);
      }
    }
    if (tid == 0) {
      if (FAST) {
        if (l > 0 && pready <= t) {  // need prev flag for step t+1; amortize via lookahead
          int la = t + 4; if (la > 253) la = 253;
          const int* p1 = (const int*)(fll + (size_t)((l - 1) * FSTRIDE + t + 1) * 16);
          const int* p2 = (const int*)(fll + (size_t)((l - 1) * FSTRIDE + la) * 16);
          for (int it = 0; it < (1 << 14); ++it) {
            int4v a, b;
            asm volatile(
                "global_load_dwordx4 %0, %2, off sc1\n\t"
                "global_load_dwordx4 %1, %3, off sc1\n\t"
                "s_waitcnt vmcnt(0)"
                : "=&v"(a), "=&v"(b) : "v"(p1), "v"(p2) : "memory");
            if (l16ok(b)) { pready = la; break; }
            if (l16ok(a)) { pready = t + 1; break; }
            __builtin_amdgcn_s_sleep(1);
          }
        }
        poll_own2((const int*)(ffl + (size_t)(l * FSTRIDE + t) * 16),
                  (const int*)(fll + (size_t)(l * FSTRIDE + t) * 16));
      } else {
        const int* fl = (const int*)(fll + (size_t)(l * FSTRIDE + t) * 16);
        const int* pl = (l > 0) ? (const int*)(fll + (size_t)((l - 1) * FSTRIDE + t + 1) * 16) : fl;
        if (l > 0) poll_slow<true>(fl, pl);
        else poll_slow<false>(fl, pl);
      }
    }
    __builtin_amdgcn_s_barrier();
    membar();

    const int arow = mb * 16 + (lane & 15);
    const f16* s0 = sbuf + (size_t)l * LSTRIDE + ((size_t)t * 32 + arow) * 768 + (size_t)q4 * 8;
    f32x4 acc = {0.f, 0.f, 0.f, 0.f};
#pragma unroll
    for (int kk = 0; kk < 24; ++kk) acc = mfma16(ldg8(s0 + (size_t)kk * 32), bf[kk < NREG ? kk : 0], acc);
    if (KK == 40) {
      const f16* s1 = sbuf + (size_t)(l - 1) * LSTRIDE + ((size_t)(t + 1) * 32 + arow) * 768 + (size_t)q4 * 8;
#pragma unroll
      for (int kk = 24; kk < 32; ++kk) acc = mfma16(ldg8(s1 + (size_t)(kk - 24) * 32), bf[kk < NREG ? kk : 0], acc);
#pragma unroll
      for (int kk = 32; kk < 40; ++kk) {
        f16x8 bb = *reinterpret_cast<const f16x8*>(bflds + ((size_t)(w * 8 + (kk - 32)) * 64 + lane) * 8);
        acc = mfma16(ldg8(s1 + (size_t)(kk - 24) * 32), bb, acc);
      }
    }

    // stage output tile in LDS
    const int scol = nt * 16 + (lane & 15);
#pragma unroll
    for (int i = 0; i < 4; ++i) {
      float v = acc[i];
      if (KK == 24) v += xadd[i];
      if (ncol < 512) v = tanh_fast(v);
      smtile[(mb * 16 + q4 * 4 + i) * 48 + scol] = (f16)v;
    }
    __syncthreads();
    {  // coalesced export: 384 threads x 8B
      int row = tid / 12; int c4 = (tid - row * 12) * 4;
      f16x4 v4 = *reinterpret_cast<const f16x4*>(smtile + row * 48 + c4);
      f16* dst = sbuf + (size_t)l * LSTRIDE + ((size_t)(t + 1) * 32 + row) * 768 + c * 48 + c4;
      if (!FAST) st8_sc1(dst, v4);          // LLC + full drain (r5 path)
      else if (l < 4) st8_fast(dst, v4);    // waits PLAIN only; sc1 drains below
      else st8_plain(dst, v4);              // l==4: k_out reads after dispatch end
    }
    __builtin_amdgcn_s_barrier();  // all waves' plain/sc1(slow) stores landed
    if (tid == 0) st_b_plain(ffl + (size_t)(l * FSTRIDE + t + 1) * 16 + c, 1);  // local flag FIRST
    if (FAST && l < 4) drain_vm();  // sc1 h-stores reach LLC (off own-layer critical path)
    __builtin_amdgcn_s_barrier();
    if (tid == 0) st_b_sc1(fll + (size_t)(l * FSTRIDE + t + 1) * 16 + c, 1);
  }
}

__global__ __launch_bounds__(384, 2) void k_rec(const f16* __restrict__ gbuf, f16* __restrict__ sbuf,
    const float* __restrict__ xw0, const float* __restrict__ w1f,
    const float* __restrict__ btf, const float* __restrict__ h0,
    const float* __restrict__ m0, unsigned char* __restrict__ ffl,
    unsigned char* __restrict__ fll, int* __restrict__ mask, int* __restrict__ ready) {
  __shared__ f16 bflds[6 * 8 * 64 * 8];
  __shared__ f16 smtile[32 * 48];
  __shared__ int s_fast;
  const int l = blockIdx.x & 7;  // round-robin dispatch: bid%8 -> XCD
  if (l >= 5) return;
  const int c = blockIdx.x >> 3;

  // runtime XCD co-location check; mask visible BEFORE ready (drain between).
  if (threadIdx.x == 0) {
    unsigned xcd = ((unsigned)__builtin_amdgcn_s_getreg(HWREG_XCC_ID)) & 15u;
    __hip_atomic_fetch_or(mask + l, (int)(1u << xcd), __ATOMIC_RELAXED, __HIP_MEMORY_SCOPE_AGENT);
    drain_vm();  // order: mask-or globally complete before ready-add is issued
    add_llc(ready);
    int ok = 0;
    for (int it = 0; it < (1 << 12); ++it) {
      if (ld_llc(ready) >= 80) { ok = 1; break; }
      __builtin_amdgcn_s_sleep(8);
    }
    int m = ld_llc(mask + l);
    s_fast = ok && m && ((m & (m - 1)) == 0);
  }
  __syncthreads();
  const bool fast = (s_fast != 0);

  if (fast) {
    if (l == 0) rec_run<24, true>(0, c, threadIdx.x, gbuf, sbuf, xw0, w1f, btf, h0, m0, ffl, fll, bflds, smtile);
    else        rec_run<40, true>(l, c, threadIdx.x, gbuf, sbuf, xw0, w1f, btf, h0, m0, ffl, fll, bflds, smtile);
  } else {
    if (l == 0) rec_run<24, false>(0, c, threadIdx.x, gbuf, sbuf, xw0, w1f, btf, h0, m0, ffl, fll, bflds, smtile);
    else        rec_run<40, false>(l, c, threadIdx.x, gbuf, sbuf, xw0, w1f, btf, h0, m0, ffl, fll, bflds, smtile);
  }
}

// ---------------- K5: output projection ----------------
__global__ __launch_bounds__(256) void k_out(const f16* __restrict__ sbuf4,
    const f16* __restrict__ outw, const float* __restrict__ outb, float* __restrict__ out) {
  const int bid = blockIdx.x; const int b = bid >> 2; const int tp0 = (bid & 3) * 64;
  const int tid = threadIdx.x, lane = tid & 63, w = tid >> 6, q4 = lane >> 4;
  f32x4 acc[3];
#pragma unroll
  for (int i = 0; i < 3; ++i) acc[i] = (f32x4){0.f, 0.f, 0.f, 0.f};
  int tq = tp0 + w * 16 + (lane & 15) + 1;
  const int tau = tq > 253 ? 253 : tq;
  const f16* arow = sbuf4 + ((size_t)tau * 32 + b) * 768 + (size_t)q4 * 8;
#pragma unroll
  for (int kk = 0; kk < 16; ++kk) {
    f16x8 a = ldg8(arow + (size_t)kk * 32);
#pragma unroll
    for (int nt2 = 0; nt2 < 3; ++nt2) {
      f16x8 bb = ldg8(outw + (size_t)(nt2 * 16 + (lane & 15)) * 512 + kk * 32 + q4 * 8);
      acc[nt2] = mfma16(a, bb, acc[nt2]);
    }
  }
#pragma unroll
  for (int nt2 = 0; nt2 < 3; ++nt2) {
    int cc = nt2 * 16 + (lane & 15);
    if (cc < 41) {
      float ob = outb[cc];
#pragma unroll
      for (int i = 0; i < 4; ++i) {
        int tp = tp0 + w * 16 + q4 * 4 + i;
        if (tp < 253) out[((size_t)b * 253 + tp) * 41 + cc] = acc[nt2][i] + ob;
      }
    }
  }
}

extern "C" void kernel_launch(void* const* d_in, const int* in_sizes, int n_in,
                              void* d_out, int out_size, void* d_ws, size_t ws_size,
                              hipStream_t stream) {
  const float* x      = (const float*)d_in[0];
  const int*   dayIdx = (const int*)d_in[1];
  const float* day_W  = (const float*)d_in[2];
  const float* day_b  = (const float*)d_in[3];
  const float* e_x0   = (const float*)d_in[4];
  const float* W_x0   = (const float*)d_in[5];
  const float* e_xr   = (const float*)d_in[6];
  const float* W_xr   = (const float*)d_in[7];
  const float* e_h    = (const float*)d_in[8];
  const float* e_m    = (const float*)d_in[9];
  const float* W_h    = (const float*)d_in[10];
  const float* W_m    = (const float*)d_in[11];
  const float* h0     = (const float*)d_in[12];
  const float* m0     = (const float*)d_in[13];
  const float* out_W  = (const float*)d_in[14];
  const float* out_b  = (const float*)d_in[15];
  float* outp = (float*)d_out;

  char* w = (char*)d_ws;
  size_t o = 0;
  auto al = [&](size_t n) { void* p = w + o; o = (o + n + 255) & ~(size_t)255; return p; };

  // flags layout (FSTRIDE=256 -> 4KB-aligned per-layer regions):
  // [0,20480) ffl ; [20480,40960) fll ; 40960 mask[5] ; 40980 ready ; 41216 setup bar
  char*  flags = (char*) al(49152);
  f16*   gbuf  = (f16*)  al((size_t)5 * 768 * 1280 * 2);
  f16*   outw  = (f16*)  al((size_t)48 * 512 * 2);
  float* xw0   = (float*)al((size_t)8192 * 576 * 4);
  float* w1f   = (float*)al((size_t)5 * 512 * 4);
  float* btf   = (float*)al(256 * 4);

  // overlay: setup temporaries (X, AWt, dayWt, wxcat, h1) are dead before
  // k_rec writes sbuf — alias them over the sbuf region.
  const size_t XB    = ((size_t)17 * N2 * 8 + 255) & ~(size_t)255;
  const size_t AWTB  = ((size_t)5 * 512 * 256 * 4 + 255) & ~(size_t)255;
  const size_t DAYB  = ((size_t)24 * 512 * 512 * 2 + 255) & ~(size_t)255;
  const size_t WXB   = ((size_t)576 * 7168 * 2 + 255) & ~(size_t)255;
  const size_t H1B   = ((size_t)32 * 1024 * 512 * 2 + 255) & ~(size_t)255;
  const size_t SBUFB = (size_t)5 * LSTRIDE * 2;
  size_t ovb = XB + AWTB + DAYB + WXB + H1B;
  if (SBUFB > ovb) ovb = SBUFB;
  char* ov = (char*)al(ovb);
  double* X     = (double*)ov;
  float*  AWt   = (float*)(ov + XB);
  f16*    dayWt = (f16*)(ov + XB + AWTB);
  f16*    wxcat = (f16*)(ov + XB + AWTB + DAYB);
  f16*    h1    = (f16*)(ov + XB + AWTB + DAYB + WXB);
  f16*    sbuf  = (f16*)ov;

  if (o > ws_size) return;  // workspace too small -> fail loudly
  (void)in_sizes; (void)n_in; (void)out_size;

  hipMemsetAsync(flags, 0, 49152, stream);
  k_setup<<<128, 256, 0, stream>>>(day_W, e_x0, W_x0, e_xr, W_xr, e_h, e_m, W_h, W_m,
                                   out_W, X, w1f, AWt, btf, gbuf, wxcat, outw, dayWt,
                                   (int*)(flags + 41216));
  k_day<<<1024, 256, 0, stream>>>(x, dayIdx, day_b, dayWt, h1);
  k_xw0<<<384, 256, 0, stream>>>(h1, wxcat, xw0);
  k_rec<<<128, 384, 0, stream>>>(gbuf, sbuf, xw0, w1f, btf, h0, m0,
                                 (unsigned char*)flags, (unsigned char*)(flags + 20480),
                                 (int*)(flags + 40960), (int*)(flags + 40980));
  k_out<<<128, 256, 0, stream>>>(sbuf + (size_t)4 * LSTRIDE, outw, out_b, outp);
}

// Round 10
// 4166.499 us; speedup vs baseline: 14.8320x; 14.8320x over previous
//
#include <hip/hip_runtime.h>
#include <hip/hip_fp16.h>

typedef _Float16 f16;
typedef _Float16 f16x8 __attribute__((ext_vector_type(8)));
typedef _Float16 f16x4 __attribute__((ext_vector_type(4)));
typedef float f32x4 __attribute__((ext_vector_type(4)));
typedef int int4v __attribute__((ext_vector_type(4)));

#define DI static __device__ __forceinline__

constexpr int N2 = 257 * 257;
#define LSTRIDE ((size_t)254 * 32 * 768)
#define HWREG_XCC_ID 63508  // hwreg(id=20, offset=0, size=32)
#define FSTRIDE 256

DI f32x4 mfma16(f16x8 a, f16x8 b, f32x4 c) {
  return __builtin_amdgcn_mfma_f32_16x16x32_f16(a, b, c, 0, 0, 0);
}
DI f16x8 ldg8(const f16* p) { return *reinterpret_cast<const f16x8*>(p); }
DI f16x8 cvt8(const float* s) {
  f16x8 v;
#pragma unroll
  for (int j = 0; j < 8; ++j) v[j] = (f16)s[j];
  return v;
}
DI double invfact(int k) {
  double f = 1.0;
  for (int i = 2; i <= k; ++i) f *= (double)i;
  return 1.0 / f;
}

// ---- visibility helpers ----
DI void st_d_sc1(double* p, double v) {
  asm volatile("global_store_dwordx2 %0, %1, off sc1" :: "v"(p), "v"(v) : "memory");
}
DI void st_f_sc1(float* p, float v) {
  asm volatile("global_store_dword %0, %1, off sc1" :: "v"(p), "v"(v) : "memory");
}
DI void st_h_sc1(f16* p, f16 v) {
  asm volatile("global_store_short %0, %1, off sc1" :: "v"(p), "v"(v) : "memory");
}
DI void st_b_sc1(unsigned char* p, int v) {
  asm volatile("global_store_byte %0, %1, off sc1" :: "v"(p), "v"(v) : "memory");
}
DI void st8_sc1(f16* p, f16x4 v) {
  asm volatile("global_store_dwordx2 %0, %1, off sc1\n\ts_waitcnt vmcnt(0)"
               :: "v"(p), "v"(v) : "memory");
}
DI void st8_plain(f16* p, f16x4 v) {
  asm volatile("global_store_dwordx2 %0, %1, off\n\ts_waitcnt vmcnt(0)"
               :: "v"(p), "v"(v) : "memory");
}
DI void st8_fast(f16* p, f16x4 v) {
  // plain (local L2) + sc1 (LLC write-through); vmcnt(1): in-order vmcnt retire
  // => the PLAIN (older) store is complete; the sc1 store drains later.
  asm volatile(
      "global_store_dwordx2 %0, %1, off\n\t"
      "global_store_dwordx2 %0, %1, off sc1\n\t"
      "s_waitcnt vmcnt(1)"
      :: "v"(p), "v"(v) : "memory");
}
DI void atomic_bump_l2(int* p) {  // plain RMW: executes at the local XCD L2
  int one = 1;
  asm volatile("global_atomic_add %0, %1, off" :: "v"(p), "v"(one) : "memory");
}
DI int atomic_read_l2(int* p) {  // add-0 with return: guaranteed L2-coherent read
  int v, zero = 0;
  asm volatile("global_atomic_add %0, %1, %2, off sc0\n\ts_waitcnt vmcnt(0)"
               : "=v"(v) : "v"(p), "v"(zero) : "memory");
  return v;
}
DI int ld_llc(const int* p) {
  return __hip_atomic_load(p, __ATOMIC_RELAXED, __HIP_MEMORY_SCOPE_AGENT);
}
DI void add_llc(int* p) {
  __hip_atomic_fetch_add(p, 1, __ATOMIC_RELAXED, __HIP_MEMORY_SCOPE_AGENT);
}
DI int fetchadd_llc(int* p) {
  return __hip_atomic_fetch_add(p, 1, __ATOMIC_RELAXED, __HIP_MEMORY_SCOPE_AGENT);
}
DI void drain_vm() { asm volatile("s_waitcnt vmcnt(0)" ::: "memory"); }
DI void membar() {
  __builtin_amdgcn_sched_barrier(0);
  asm volatile("" ::: "memory");
}
DI bool l16ok(int4v a) {
  return a.x == 0x01010101 && a.y == 0x01010101 && a.z == 0x01010101 && a.w == 0x01010101;
}
DI int4v ld16_sc1(const int* p) {
  int4v b;
  asm volatile("global_load_dwordx4 %0, %1, off sc1\n\ts_waitcnt vmcnt(0)"
               : "=v"(b) : "v"(p) : "memory");
  return b;
}
template <bool HASP>
DI void poll_slow(const int* fl, const int* pl) {
  for (int it = 0; it < (1 << 14); ++it) {
    int4v b, c;
    asm volatile(
        "global_load_dwordx4 %0, %2, off sc1\n\t"
        "global_load_dwordx4 %1, %3, off sc1\n\t"
        "s_waitcnt vmcnt(0)"
        : "=&v"(b), "=&v"(c)
        : "v"(fl), "v"(pl) : "memory");
    bool prv = HASP ? l16ok(c) : true;
    if (l16ok(b) & prv) return;
    __builtin_amdgcn_s_sleep(1);
  }
}
DI float tanh_fast(float x) {
  x = fminf(9.f, fmaxf(-9.f, x));
  float e = __expf(2.f * x);
  return __fdividef(e - 1.f, e + 1.f);
}

// fence-free counting barrier (k_setup only)
DI void gridbar_nf(int* bar, int nwg) {
  drain_vm();
  __syncthreads();
  if (threadIdx.x == 0) {
    int g = ld_llc(bar + 1);
    int old = __hip_atomic_fetch_add(bar, 1, __ATOMIC_RELAXED, __HIP_MEMORY_SCOPE_AGENT);
    if (old == nwg - 1) {
      __hip_atomic_store(bar, 0, __ATOMIC_RELAXED, __HIP_MEMORY_SCOPE_AGENT);
      add_llc(bar + 1);
    } else {
      for (int it = 0; it < (1 << 14) && ld_llc(bar + 1) == g; ++it)
        __builtin_amdgcn_s_sleep(1);
    }
  }
  __syncthreads();
}

DI void mm257(double* __restrict__ D, const double* __restrict__ A, const double* __restrict__ Bm,
              int fj, const double* __restrict__ T1, const double* __restrict__ T2,
              const double* __restrict__ T3, int gtid, int nth) {
  double c0 = 0, c1 = 0, c2 = 0, c3 = 0;
  if (fj >= 0) {
    c0 = invfact(4 * fj); c1 = invfact(4 * fj + 1);
    c2 = invfact(4 * fj + 2); c3 = invfact(4 * fj + 3);
  }
  for (int e = gtid; e < N2; e += nth) {
    int i = e / 257, j = e - i * 257;
    const double* ar = A + (size_t)i * 257;
    const double* bc = Bm + j;
    double s0 = 0, s1 = 0, s2 = 0, s3 = 0;
    for (int k = 0; k < 256; k += 4) {
      s0 = fma(ar[k], bc[(size_t)k * 257], s0);
      s1 = fma(ar[k + 1], bc[(size_t)(k + 1) * 257], s1);
      s2 = fma(ar[k + 2], bc[(size_t)(k + 2) * 257], s2);
      s3 = fma(ar[k + 3], bc[(size_t)(k + 3) * 257], s3);
    }
    double s = ((s0 + s1) + (s2 + s3)) + ar[256] * bc[(size_t)256 * 257];
    if (fj >= 0) s += c0 * ((i == j) ? 1.0 : 0.0) + c1 * T1[e] + c2 * T2[e] + c3 * T3[e];
    st_d_sc1(D + e, s);
  }
}

// ---------------- K1: expm + all precomputation ----------------
__global__ __launch_bounds__(256) void k_setup(
    const float* __restrict__ dayW, const float* __restrict__ ex0, const float* __restrict__ Wx0,
    const float* __restrict__ exr, const float* __restrict__ Wxr,
    const float* __restrict__ eh, const float* __restrict__ em,
    const float* __restrict__ Wh, const float* __restrict__ Wm, const float* __restrict__ outW,
    double* __restrict__ X, float* __restrict__ w1f, float* __restrict__ AWt,
    float* __restrict__ btf, f16* __restrict__ gbuf, f16* __restrict__ wxcat,
    f16* __restrict__ outw, f16* __restrict__ dayWt, int* __restrict__ bar) {
  const int gtid = blockIdx.x * 256 + threadIdx.x;
  const int nth = 128 * 256;
  double* Ms = X;
  double* M2 = X + N2;
  double* M3 = X + 2 * N2;
  double* M4 = X + 3 * N2;
  double* H = X + 4 * N2;
  double* S = X + 11 * N2;

  for (int e = gtid; e < N2; e += nth) {
    int i = e / 257, j = e - i * 257;
    double v = 0.0;
    if (i < 256) {
      double R = (2.0 * i + 1.0) / 256.0;
      if (j < 256) v = R * ((i < j) ? -1.0 : (((i - j) & 1) ? 1.0 : -1.0));
      else v = R * ((i & 1) ? -1.0 : 1.0);
    }
    st_d_sc1(Ms + e, v / 64.0);
  }
  for (int e = gtid; e < 576 * 896; e += nth) {
    int n = e / 896, kc = (e - n * 896) * 8;
    f16x8 v;
    if (n < 512) v = cvt8(Wx0 + (size_t)n * 7168 + kc);
    else if (n == 512) v = cvt8(ex0 + kc);
    else {
#pragma unroll
      for (int j = 0; j < 8; ++j) v[j] = (f16)0.f;
    }
    *reinterpret_cast<f16x8*>(wxcat + (size_t)n * 7168 + kc) = v;
  }
  for (int e = gtid; e < 48 * 64; e += nth) {
    int n = e / 64, kc = (e - n * 64) * 8;
    f16x8 v;
    if (n < 41) v = cvt8(outW + (size_t)n * 512 + kc);
    else {
#pragma unroll
      for (int j = 0; j < 8; ++j) v[j] = (f16)0.f;
    }
    *reinterpret_cast<f16x8*>(outw + (size_t)n * 512 + kc) = v;
  }
  {
    __shared__ float tile[64][65];
    for (int tt = blockIdx.x; tt < 24 * 64; tt += 128) {
      int D = tt >> 6; int r = tt & 63; int kb = (r >> 3) * 64; int nb = (r & 7) * 64;
      __syncthreads();
      for (int q = 0; q < 16; ++q) {
        int idx = threadIdx.x + q * 256; int kk = idx >> 6; int nn = idx & 63;
        tile[kk][nn] = dayW[(size_t)D * 262144 + (size_t)(kb + kk) * 512 + nb + nn];
      }
      __syncthreads();
      for (int q = 0; q < 2; ++q) {
        int cidx = threadIdx.x + q * 256; int nn = cidx >> 3; int kc = (cidx & 7) * 8;
        f16x8 v;
#pragma unroll
        for (int jj = 0; jj < 8; ++jj) v[jj] = (f16)tile[kc + jj][nn];
        *reinterpret_cast<f16x8*>(dayWt + (size_t)D * 262144 + (size_t)(nb + nn) * 512 + kb + kc) = v;
      }
    }
    __syncthreads();
  }
  gridbar_nf(bar, 128);

  mm257(M2, Ms, Ms, -1, Ms, Ms, Ms, gtid, nth); gridbar_nf(bar, 128);
  mm257(M3, M2, Ms, -1, Ms, Ms, Ms, gtid, nth); gridbar_nf(bar, 128);
  mm257(M4, M2, M2, -1, Ms, Ms, Ms, gtid, nth);
  for (int e = gtid; e < N2; e += nth) {
    int i = e / 257, j = e - i * 257;
    st_d_sc1(H + e, (i == j) ? invfact(24) : 0.0);
  }
  gridbar_nf(bar, 128);
  for (int k = 0; k < 6; ++k) {
    mm257(H + (size_t)(k + 1) * N2, H + (size_t)k * N2, M4, 5 - k, Ms, M2, M3, gtid, nth);
    gridbar_nf(bar, 128);
  }
  {
    const double* Ssrc = H + (size_t)6 * N2;
    for (int k = 0; k < 6; ++k) {
      mm257(S + (size_t)k * N2, Ssrc, Ssrc, -1, Ms, Ms, Ms, gtid, nth);
      gridbar_nf(bar, 128);
      Ssrc = S + (size_t)k * N2;
    }
  }
  const double* E = S + (size_t)5 * N2;

  for (int e = gtid; e < 256; e += nth) st_f_sc1(btf + e, (float)E[(size_t)e * 257 + 256]);
  for (int e = gtid; e < 5 * 512; e += nth) {
    int l = e / 512, n = e - l * 512;
    const float* wm = Wm + ((size_t)l * 512 + n) * 256;
    float s = 0.f;
    for (int j = 0; j < 256; ++j) s += (float)E[(size_t)j * 257 + 256] * wm[j];
    st_f_sc1(w1f + e, s);
  }
  for (int e = gtid; e < 5 * 512 * 256; e += nth) {
    int l = e / (512 * 256); int r = e - l * 512 * 256; int n = r >> 8; int i = r & 255;
    const double* Ec = E + i;
    const float* wm = Wm + ((size_t)l * 512 + n) * 256;
    float s0 = 0, s1 = 0, s2 = 0, s3 = 0;
    for (int j = 0; j < 256; j += 4) {
      s0 += (float)Ec[(size_t)j * 257] * wm[j];
      s1 += (float)Ec[(size_t)(j + 1) * 257] * wm[j + 1];
      s2 += (float)Ec[(size_t)(j + 2) * 257] * wm[j + 2];
      s3 += (float)Ec[(size_t)(j + 3) * 257] * wm[j + 3];
    }
    st_f_sc1(AWt + e, (s0 + s1) + (s2 + s3));
  }
  gridbar_nf(bar, 128);

  for (int e = gtid; e < 5 * 768 * 160; e += nth) {
    int l = e / (768 * 160); int r = e - l * 768 * 160; int n = r / 160; int k = (r - n * 160) * 8;
    if (l == 0 && k >= 768) continue;
    f16x8 v;
    if (n < 512) {
      float w1n = w1f[l * 512 + n];
      if (k < 512) {
        const float* a = Wh + ((size_t)l * 512 + n) * 512 + k;
        const float* b = eh + (size_t)l * 512 + k;
#pragma unroll
        for (int jj = 0; jj < 8; ++jj) v[jj] = (f16)(a[jj] + b[jj] * w1n);
      } else if (k < 768) {
        int i = k - 512;
        const float* a = AWt + ((size_t)l * 512 + n) * 256 + i;
        const float* b = em + (size_t)l * 256 + i;
#pragma unroll
        for (int jj = 0; jj < 8; ++jj) v[jj] = (f16)(a[jj] + b[jj] * w1n);
      } else {
        int d = k - 768;
        const float* a = Wxr + ((size_t)(l - 1) * 512 + n) * 512 + d;
        const float* b = exr + (size_t)(l - 1) * 512 + d;
#pragma unroll
        for (int jj = 0; jj < 8; ++jj) v[jj] = (f16)(a[jj] + b[jj] * w1n);
      }
    } else {
      int jm = n - 512;
      float btn = btf[jm];
      if (k < 512) {
        const float* b = eh + (size_t)l * 512 + k;
#pragma unroll
        for (int jj = 0; jj < 8; ++jj) v[jj] = (f16)(b[jj] * btn);
      } else if (k < 768) {
        int i = k - 512;
        const double* a = E + (size_t)jm * 257 + i;
        const float* b = em + (size_t)l * 256 + i;
#pragma unroll
        for (int jj = 0; jj < 8; ++jj) v[jj] = (f16)((float)a[jj] + b[jj] * btn);
      } else {
        int d = k - 768;
        const float* b = exr + (size_t)(l - 1) * 512 + d;
#pragma unroll
        for (int jj = 0; jj < 8; ++jj) v[jj] = (f16)(b[jj] * btn);
      }
    }
    *reinterpret_cast<f16x8*>(gbuf + ((size_t)l * 768 + n) * 1280 + k) = v;
  }
}

// ---------------- K2: day-specific linear + softsign ----------------
__global__ __launch_bounds__(256) void k_day(const float* __restrict__ x,
    const int* __restrict__ dayIdx, const float* __restrict__ dayb,
    const f16* __restrict__ dayWt, f16* __restrict__ h1) {
  __shared__ f16 As[64][40];
  __shared__ f16 Bs[256][40];
  const int bid = blockIdx.x;
  const int b = bid >> 5; const int r = bid & 31;
  const int t0 = (r >> 1) * 64; const int n0 = (r & 1) * 256;
  const int D = dayIdx[b];
  const int tid = threadIdx.x, lane = tid & 63, w = tid >> 6, q4 = lane >> 4;
  const float* xb = x + ((size_t)b * 1024 + t0) * 512;
  const f16* Wt = dayWt + (size_t)D * 262144 + (size_t)n0 * 512;
  f32x4 acc[16];
#pragma unroll
  for (int i = 0; i < 16; ++i) acc[i] = (f32x4){0.f, 0.f, 0.f, 0.f};
  for (int kt = 0; kt < 16; ++kt) {
    const int k0 = kt * 32;
    __syncthreads();
    { int row = tid >> 2, c8 = (tid & 3) * 8;
      *reinterpret_cast<f16x8*>(&As[row][c8]) = cvt8(xb + (size_t)row * 512 + k0 + c8); }
    for (int q = 0; q < 4; ++q) {
      int idx = tid + q * 256; int row = idx >> 2; int c8 = (idx & 3) * 8;
      *reinterpret_cast<f16x8*>(&Bs[row][c8]) = ldg8(Wt + (size_t)row * 512 + k0 + c8);
    }
    __syncthreads();
    f16x8 a = *reinterpret_cast<const f16x8*>(&As[w * 16 + (lane & 15)][q4 * 8]);
#pragma unroll
    for (int nt2 = 0; nt2 < 16; ++nt2) {
      f16x8 bb = *reinterpret_cast<const f16x8*>(&Bs[nt2 * 16 + (lane & 15)][q4 * 8]);
      acc[nt2] = mfma16(a, bb, acc[nt2]);
    }
  }
#pragma unroll
  for (int nt2 = 0; nt2 < 16; ++nt2) {
    int n = n0 + nt2 * 16 + (lane & 15);
    float db = dayb[(size_t)D * 512 + n];
#pragma unroll
    for (int i = 0; i < 4; ++i) {
      int t = t0 + w * 16 + q4 * 4 + i;
      float v = acc[nt2][i] + db;
      v = v / (1.f + fabsf(v));
      h1[((size_t)b * 1024 + t) * 512 + n] = (f16)v;
    }
  }
}

// ---------------- K3: layer-0 input GEMM ----------------
__global__ __launch_bounds__(256) void k_xw0(const f16* __restrict__ h1,
    const f16* __restrict__ wxcat, float* __restrict__ xw0) {
  __shared__ f16 As[128][40];
  __shared__ f16 Bs[96][40];
  const int bid = blockIdx.x;
  const int mt = bid / 6; const int nb = bid - mt * 6;
  const int m0 = mt * 128; const int n0 = nb * 96;
  const int tid = threadIdx.x, lane = tid & 63, w = tid >> 6, q4 = lane >> 4;
  f32x4 acc[2][6];
#pragma unroll
  for (int a = 0; a < 2; ++a)
#pragma unroll
    for (int b = 0; b < 6; ++b) acc[a][b] = (f32x4){0.f, 0.f, 0.f, 0.f};
  for (int kt = 0; kt < 224; ++kt) {
    const int k0 = kt * 32; const int p = k0 >> 9; const int kd = k0 & 511;
    __syncthreads();
    for (int q = 0; q < 2; ++q) {
      int idx = tid + q * 256; int row = idx >> 2; int c8 = (idx & 3) * 8;
      int m = m0 + row; int b = m >> 8; int tp = m & 255; if (tp > 252) tp = 252;
      *reinterpret_cast<f16x8*>(&As[row][c8]) =
          ldg8(h1 + ((size_t)b * 1024 + (size_t)tp * 4 + p) * 512 + kd + c8);
    }
    for (int q = 0; q < 2; ++q) {
      int idx = tid + q * 256;
      if (idx < 384) {
        int row = idx >> 2; int c8 = (idx & 3) * 8;
        *reinterpret_cast<f16x8*>(&Bs[row][c8]) =
            ldg8(wxcat + (size_t)(n0 + row) * 7168 + k0 + c8);
      }
    }
    __syncthreads();
#pragma unroll
    for (int mb = 0; mb < 2; ++mb) {
      f16x8 a = *reinterpret_cast<const f16x8*>(&As[w * 32 + mb * 16 + (lane & 15)][q4 * 8]);
#pragma unroll
      for (int nt2 = 0; nt2 < 6; ++nt2) {
        f16x8 bb = *reinterpret_cast<const f16x8*>(&Bs[nt2 * 16 + (lane & 15)][q4 * 8]);
        acc[mb][nt2] = mfma16(a, bb, acc[mb][nt2]);
      }
    }
  }
#pragma unroll
  for (int mb = 0; mb < 2; ++mb)
#pragma unroll
    for (int nt2 = 0; nt2 < 6; ++nt2)
#pragma unroll
      for (int i = 0; i < 4; ++i) {
        int m = m0 + w * 32 + mb * 16 + q4 * 4 + i;
        int n = n0 + nt2 * 16 + (lane & 15);
        xw0[(size_t)m * 576 + n] = acc[mb][nt2][i];
      }
}

// ---------------- K4: recurrence (constructed XCD co-location) ----------------
// Flag regions:
//  fastL: local counters, dword at l*4096 + t*16      [0, 20480)
//  fastX: LLC bitmap, byte at (l*256+t)*16 + c        [20480, 40960)
//  slowF: LLC bitmap (slow mode, r5 protocol)         [40960, 61440)
template <int KK, bool FAST>
DI void rec_run(int l, int c, int tid, const f16* __restrict__ gbuf, f16* __restrict__ sbuf,
                const float* __restrict__ xw0, const float* __restrict__ w1f,
                const float* __restrict__ btf, const float* __restrict__ h0,
                const float* __restrict__ m0, char* fastL, unsigned char* fastX,
                unsigned char* slowF, f16* bflds, f16* smtile) {
  const int lane = tid & 63, w = tid >> 6;
  const int mb = w / 3, nt = w % 3;
  const int nbase = c * 48 + nt * 16;
  const int ncol = nbase + (lane & 15);
  const int q4 = lane >> 4;

  // ---- t=0 state init ----
  for (int r = tid; r < 32 * 48; r += 384) {
    int row = r / 48; int col = c * 48 + (r - row * 48);
    float v = (col < 512) ? h0[(size_t)l * 512 + col] : m0[(size_t)l * 256 + col - 512];
    f16* p = sbuf + (size_t)l * LSTRIDE + (size_t)row * 768 + col;
    if (FAST) *p = (f16)v;  // only own layer reads t=0 -> local L2 suffices
    else st_h_sc1(p, (f16)v);
  }

  // ---- weights ----
  const f16* gb = gbuf + ((size_t)l * 768 + ncol) * 1280 + (size_t)q4 * 8;
  constexpr int NREG = (KK > 32) ? 32 : KK;
  f16x8 bf[NREG];
#pragma unroll
  for (int kk = 0; kk < NREG; ++kk) bf[kk] = ldg8(gb + (size_t)kk * 32);
  if (KK == 40) {
#pragma unroll
    for (int kk = 32; kk < 40; ++kk) {
      f16x8 v = ldg8(gb + (size_t)kk * 32);
      *reinterpret_cast<f16x8*>(bflds + ((size_t)(w * 8 + (kk - 32)) * 64 + lane) * 8) = v;
    }
  }
  float w1n = 0.f, btn = 0.f;
  if (KK == 24) {
    if (ncol < 512) w1n = w1f[ncol];
    else btn = btf[ncol - 512];
  }
  drain_vm();
  __syncthreads();
  if (tid == 0) {
    if (FAST) {
      atomic_bump_l2((int*)(fastL + (size_t)l * 4096));      // cnt[l][0]
      st_b_sc1(fastX + (size_t)(l * 256) * 16 + c, 1);       // LLC bitmap t=0
    } else {
      st_b_sc1(slowF + (size_t)(l * FSTRIDE) * 16 + c, 1);
    }
  }

  int pready = 0;   // prev-layer confirmed through step index pready (tid0)
  int lwin = 64, lfails = 0;  // local-poll hysteresis (tid0)

  for (int t = 0; t < 253; ++t) {
    float xadd[4];
    if (KK == 24) {
#pragma unroll
      for (int i = 0; i < 4; ++i) {
        const int brow = mb * 16 + q4 * 4 + i;
        const float* xr = xw0 + ((size_t)brow * 256 + t) * 576;
        float xe = xr[512];
        xadd[i] = (ncol < 512) ? (xr[ncol] + xe * w1n) : (xe * btn);
      }
    }
    if (tid == 0) {
      if (FAST) {
        if (l > 0 && pready <= t) {  // cross-layer via LLC bitmap + lookahead
          int la = t + 4; if (la > 253) la = 253;
          const int* p1 = (const int*)(fastX + (size_t)((l - 1) * 256 + t + 1) * 16);
          const int* p2 = (const int*)(fastX + (size_t)((l - 1) * 256 + la) * 16);
          for (int it = 0; it < (1 << 14); ++it) {
            int4v a, b;
            asm volatile(
                "global_load_dwordx4 %0, %2, off sc1\n\t"
                "global_load_dwordx4 %1, %3, off sc1\n\t"
                "s_waitcnt vmcnt(0)"
                : "=&v"(a), "=&v"(b) : "v"(p1), "v"(p2) : "memory");
            if (l16ok(b)) { pready = la; break; }
            if (l16ok(a)) { pready = t + 1; break; }
            __builtin_amdgcn_s_sleep(1);
          }
        }
        // own-layer: local-L2 atomic counter poll, hysteresis + LLC fallback
        int* cl = (int*)(fastL + (size_t)l * 4096 + (size_t)t * 16);
        bool got = false;
        for (int it = 0; it < lwin; ++it) {
          if (atomic_read_l2(cl) >= 16) { got = true; break; }
          __builtin_amdgcn_s_sleep(1);
        }
        if (!got) {
          if (++lfails >= 3) lwin = 4;
          const int* fx = (const int*)(fastX + (size_t)(l * 256 + t) * 16);
          for (int j = 0; j < (1 << 14); ++j) {
            if (atomic_read_l2(cl) >= 16) break;
            if (l16ok(ld16_sc1(fx))) break;
            __builtin_amdgcn_s_sleep(1);
          }
        }
      } else {
        const int* fl = (const int*)(slowF + (size_t)(l * FSTRIDE + t) * 16);
        const int* pl = (l > 0) ? (const int*)(slowF + (size_t)((l - 1) * FSTRIDE + t + 1) * 16) : fl;
        if (l > 0) poll_slow<true>(fl, pl);
        else poll_slow<false>(fl, pl);
      }
    }
    __builtin_amdgcn_s_barrier();
    membar();

    const int arow = mb * 16 + (lane & 15);
    const f16* s0 = sbuf + (size_t)l * LSTRIDE + ((size_t)t * 32 + arow) * 768 + (size_t)q4 * 8;
    f32x4 acc = {0.f, 0.f, 0.f, 0.f};
#pragma unroll
    for (int kk = 0; kk < 24; ++kk) acc = mfma16(ldg8(s0 + (size_t)kk * 32), bf[kk < NREG ? kk : 0], acc);
    if (KK == 40) {
      const f16* s1 = sbuf + (size_t)(l - 1) * LSTRIDE + ((size_t)(t + 1) * 32 + arow) * 768 + (size_t)q4 * 8;
#pragma unroll
      for (int kk = 24; kk < 32; ++kk) acc = mfma16(ldg8(s1 + (size_t)(kk - 24) * 32), bf[kk < NREG ? kk : 0], acc);
#pragma unroll
      for (int kk = 32; kk < 40; ++kk) {
        f16x8 bb = *reinterpret_cast<const f16x8*>(bflds + ((size_t)(w * 8 + (kk - 32)) * 64 + lane) * 8);
        acc = mfma16(ldg8(s1 + (size_t)(kk - 24) * 32), bb, acc);
      }
    }

    const int scol = nt * 16 + (lane & 15);
#pragma unroll
    for (int i = 0; i < 4; ++i) {
      float v = acc[i];
      if (KK == 24) v += xadd[i];
      if (ncol < 512) v = tanh_fast(v);
      smtile[(mb * 16 + q4 * 4 + i) * 48 + scol] = (f16)v;
    }
    __syncthreads();
    {
      int row = tid / 12; int c4 = (tid - row * 12) * 4;
      f16x4 v4 = *reinterpret_cast<const f16x4*>(smtile + row * 48 + c4);
      f16* dst = sbuf + (size_t)l * LSTRIDE + ((size_t)(t + 1) * 32 + row) * 768 + c * 48 + c4;
      if (!FAST) st8_sc1(dst, v4);
      else if (l < 4) st8_fast(dst, v4);  // plain confirmed; sc1 drains below
      else st8_plain(dst, v4);
    }
    __builtin_amdgcn_s_barrier();  // all plain (or sc1-slow) state stores landed
    if (FAST) {
      if (tid == 0) atomic_bump_l2((int*)(fastL + (size_t)l * 4096 + (size_t)(t + 1) * 16));
      if (l < 4) drain_vm();  // sc1 write-throughs reach LLC (off local critical path)
      __builtin_amdgcn_s_barrier();
      if (tid == 0) st_b_sc1(fastX + (size_t)(l * 256 + t + 1) * 16 + c, 1);
    } else {
      if (tid == 0) st_b_sc1(slowF + (size_t)(l * FSTRIDE + t + 1) * 16 + c, 1);
    }
  }
}

__global__ __launch_bounds__(384, 2) void k_rec(const f16* __restrict__ gbuf, f16* __restrict__ sbuf,
    const float* __restrict__ xw0, const float* __restrict__ w1f,
    const float* __restrict__ btf, const float* __restrict__ h0,
    const float* __restrict__ m0, char* __restrict__ fastL,
    unsigned char* __restrict__ fastX, unsigned char* __restrict__ slowF,
    int* __restrict__ xcdcnt, int* __restrict__ globalcnt, int* __restrict__ verdict) {
  __shared__ f16 bflds[6 * 8 * 64 * 8];
  __shared__ f16 smtile[32 * 48];
  __shared__ int sh[4];  // l, c, serve, fast

  // ---- registration & verdict: co-location by construction ----
  if (threadIdx.x == 0) {
    unsigned xcd = ((unsigned)__builtin_amdgcn_s_getreg(HWREG_XCC_ID)) & 7u;
    int pt = fetchadd_llc(xcdcnt + xcd);
    drain_vm();  // xcd ticket globally visible before the global ticket
    int gt = fetchadd_llc(globalcnt);
    if (gt == 255) {  // decider: all 256 registered (co-resident by capacity)
      int ok = 1;
      for (int i = 0; i < 5; ++i)
        if (ld_llc(xcdcnt + i) < 16) ok = 0;
      __hip_atomic_store(verdict, ok ? 1 : 2, __ATOMIC_RELAXED, __HIP_MEMORY_SCOPE_AGENT);
    }
    int v = 0;
    for (int it = 0; it < (1 << 17); ++it) {
      v = ld_llc(verdict);
      if (v) break;
      __builtin_amdgcn_s_sleep(4);
    }
    if (v == 0) v = 2;
    int L = -1, C = 0;
    if (v == 1) {
      if (xcd < 5 && pt < 16) { L = (int)xcd; C = pt; }
    } else {
      if (gt < 80) { L = gt >> 4; C = gt & 15; }
    }
    sh[0] = L; sh[1] = C; sh[2] = (L >= 0); sh[3] = (v == 1);
  }
  __syncthreads();
  if (!sh[2]) return;
  const int l = sh[0], c = sh[1];
  const bool fast = (sh[3] != 0);

  if (fast) {
    if (l == 0) rec_run<24, true>(0, c, threadIdx.x, gbuf, sbuf, xw0, w1f, btf, h0, m0, fastL, fastX, slowF, bflds, smtile);
    else        rec_run<40, true>(l, c, threadIdx.x, gbuf, sbuf, xw0, w1f, btf, h0, m0, fastL, fastX, slowF, bflds, smtile);
  } else {
    if (l == 0) rec_run<24, false>(0, c, threadIdx.x, gbuf, sbuf, xw0, w1f, btf, h0, m0, fastL, fastX, slowF, bflds, smtile);
    else        rec_run<40, false>(l, c, threadIdx.x, gbuf, sbuf, xw0, w1f, btf, h0, m0, fastL, fastX, slowF, bflds, smtile);
  }
}

// ---------------- K5: output projection ----------------
__global__ __launch_bounds__(256) void k_out(const f16* __restrict__ sbuf4,
    const f16* __restrict__ outw, const float* __restrict__ outb, float* __restrict__ out) {
  const int bid = blockIdx.x; const int b = bid >> 2; const int tp0 = (bid & 3) * 64;
  const int tid = threadIdx.x, lane = tid & 63, w = tid >> 6, q4 = lane >> 4;
  f32x4 acc[3];
#pragma unroll
  for (int i = 0; i < 3; ++i) acc[i] = (f32x4){0.f, 0.f, 0.f, 0.f};
  int tq = tp0 + w * 16 + (lane & 15) + 1;
  const int tau = tq > 253 ? 253 : tq;
  const f16* arow = sbuf4 + ((size_t)tau * 32 + b) * 768 + (size_t)q4 * 8;
#pragma unroll
  for (int kk = 0; kk < 16; ++kk) {
    f16x8 a = ldg8(arow + (size_t)kk * 32);
#pragma unroll
    for (int nt2 = 0; nt2 < 3; ++nt2) {
      f16x8 bb = ldg8(outw + (size_t)(nt2 * 16 + (lane & 15)) * 512 + kk * 32 + q4 * 8);
      acc[nt2] = mfma16(a, bb, acc[nt2]);
    }
  }
#pragma unroll
  for (int nt2 = 0; nt2 < 3; ++nt2) {
    int cc = nt2 * 16 + (lane & 15);
    if (cc < 41) {
      float ob = outb[cc];
#pragma unroll
      for (int i = 0; i < 4; ++i) {
        int tp = tp0 + w * 16 + q4 * 4 + i;
        if (tp < 253) out[((size_t)b * 253 + tp) * 41 + cc] = acc[nt2][i] + ob;
      }
    }
  }
}

extern "C" void kernel_launch(void* const* d_in, const int* in_sizes, int n_in,
                              void* d_out, int out_size, void* d_ws, size_t ws_size,
                              hipStream_t stream) {
  const float* x      = (const float*)d_in[0];
  const int*   dayIdx = (const int*)d_in[1];
  const float* day_W  = (const float*)d_in[2];
  const float* day_b  = (const float*)d_in[3];
  const float* e_x0   = (const float*)d_in[4];
  const float* W_x0   = (const float*)d_in[5];
  const float* e_xr   = (const float*)d_in[6];
  const float* W_xr   = (const float*)d_in[7];
  const float* e_h    = (const float*)d_in[8];
  const float* e_m    = (const float*)d_in[9];
  const float* W_h    = (const float*)d_in[10];
  const float* W_m    = (const float*)d_in[11];
  const float* h0     = (const float*)d_in[12];
  const float* m0     = (const float*)d_in[13];
  const float* out_W  = (const float*)d_in[14];
  const float* out_b  = (const float*)d_in[15];
  float* outp = (float*)d_out;

  char* w = (char*)d_ws;
  size_t o = 0;
  auto al = [&](size_t n) { void* p = w + o; o = (o + n + 255) & ~(size_t)255; return p; };

  // flags: [0,20480) fastL counters ; [20480,40960) fastX bitmap ;
  // [40960,61440) slowF bitmap ; 61440 xcdcnt[8] ; 61472 globalcnt ;
  // 61476 verdict ; 61504 setup barrier
  char*  flags = (char*) al(65536);
  f16*   gbuf  = (f16*)  al((size_t)5 * 768 * 1280 * 2);
  f16*   outw  = (f16*)  al((size_t)48 * 512 * 2);
  float* xw0   = (float*)al((size_t)8192 * 576 * 4);
  float* w1f   = (float*)al((size_t)5 * 512 * 4);
  float* btf   = (float*)al(256 * 4);

  const size_t XB    = ((size_t)17 * N2 * 8 + 255) & ~(size_t)255;
  const size_t AWTB  = ((size_t)5 * 512 * 256 * 4 + 255) & ~(size_t)255;
  const size_t DAYB  = ((size_t)24 * 512 * 512 * 2 + 255) & ~(size_t)255;
  const size_t WXB   = ((size_t)576 * 7168 * 2 + 255) & ~(size_t)255;
  const size_t H1B   = ((size_t)32 * 1024 * 512 * 2 + 255) & ~(size_t)255;
  const size_t SBUFB = (size_t)5 * LSTRIDE * 2;
  size_t ovb = XB + AWTB + DAYB + WXB + H1B;
  if (SBUFB > ovb) ovb = SBUFB;
  char* ov = (char*)al(ovb);
  double* X     = (double*)ov;
  float*  AWt   = (float*)(ov + XB);
  f16*    dayWt = (f16*)(ov + XB + AWTB);
  f16*    wxcat = (f16*)(ov + XB + AWTB + DAYB);
  f16*    h1    = (f16*)(ov + XB + AWTB + DAYB + WXB);
  f16*    sbuf  = (f16*)ov;

  if (o > ws_size) return;
  (void)in_sizes; (void)n_in; (void)out_size;

  hipMemsetAsync(flags, 0, 65536, stream);
  k_setup<<<128, 256, 0, stream>>>(day_W, e_x0, W_x0, e_xr, W_xr, e_h, e_m, W_h, W_m,
                                   out_W, X, w1f, AWt, btf, gbuf, wxcat, outw, dayWt,
                                   (int*)(flags + 61504));
  k_day<<<1024, 256, 0, stream>>>(x, dayIdx, day_b, dayWt, h1);
  k_xw0<<<384, 256, 0, stream>>>(h1, wxcat, xw0);
  k_rec<<<256, 384, 0, stream>>>(gbuf, sbuf, xw0, w1f, btf, h0, m0,
                                 flags, (unsigned char*)(flags + 20480),
                                 (unsigned char*)(flags + 40960),
                                 (int*)(flags + 61440), (int*)(flags + 61472),
                                 (int*)(flags + 61476));
  k_out<<<128, 256, 0, stream>>>(sbuf + (size_t)4 * LSTRIDE, outw, out_b, outp);
}